// Round 11
// baseline (62.498 us; speedup 1.0000x reference)
//
#include <hip/hip_runtime.h>
#include <math.h>

#define T1 17
#define NN 2048
#define DIN 9
#define CC 8
#define KK 5
#define NG 24                  // donor groups of 64 -> 1536 slots
#define NB 3                   // batches of 8 groups
#define NDCAP (NG * 64)        // 1536 (E[ndon]=1024, +22 sigma)
#define NQCAP 1280
#define PLANE (NN * CC)
#define XD_BYTES (T1 * NN * CC * 4)

// ---------------------------------------------------------------------------
__global__ __launch_bounds__(128) void prep_a(
    const float* __restrict__ x_all, const int* __restrict__ mask,
    unsigned* __restrict__ pm, unsigned long long* __restrict__ wsbal,
    float* __restrict__ wscol, float* __restrict__ out) {
  const int row = blockIdx.x * 128 + threadIdx.x;
  const int lane = threadIdx.x & 63;
  const int g = row >> 6;
  unsigned m = 0;
#pragma unroll
  for (int t = 0; t < T1; ++t)
    m |= (mask[t * NN + row] == 0 ? 1u : 0u) << t;
  pm[row] = m;
  const bool v = (m >> 16) & 1u;
  const unsigned long long bal = __ballot(v);

  float s[CC];
#pragma unroll
  for (int c = 0; c < CC; ++c) s[c] = 0.f;
  if (v) {
    const float* r = x_all + ((size_t)16 * NN + row) * DIN;
#pragma unroll
    for (int c = 0; c < CC; ++c) {
      const float vv = r[c];
      s[c] = vv;
      out[row * CC + c] = vv;
    }
  }
#pragma unroll
  for (int off = 32; off > 0; off >>= 1) {
#pragma unroll
    for (int c = 0; c < CC; ++c) s[c] += __shfl_down(s[c], off);
  }
  if (lane == 0) {
    wsbal[g] = bal;
#pragma unroll
    for (int c = 0; c < CC; ++c) wscol[g * CC + c] = s[c];
  }
}

// ---------------------------------------------------------------------------
__global__ __launch_bounds__(1024) void prep_b(
    const unsigned* __restrict__ pm, const unsigned long long* __restrict__ wsbal,
    const float* __restrict__ wscol, int* __restrict__ dlist,
    unsigned* __restrict__ pmd, int* __restrict__ qlist,
    float* __restrict__ colmean, int* __restrict__ cnts) {
  __shared__ int dpre[33], qpre[33];
  __shared__ unsigned long long sbal[32];
  const int tid = threadIdx.x;
  if (tid < 32) sbal[tid] = wsbal[tid];
  __syncthreads();
  if (tid == 0) {
    int a = 0, b = 0;
    for (int g = 0; g < 32; ++g) {
      dpre[g] = a;
      qpre[g] = b;
      const int p = (int)__popcll(sbal[g]);
      a += p;
      b += 64 - p;
    }
    dpre[32] = a;
    qpre[32] = b;
    cnts[0] = a;  // ndon
    cnts[1] = b;  // nq
  }
  __syncthreads();
#pragma unroll
  for (int h = 0; h < 2; ++h) {
    const int row = tid + h * 1024;
    const unsigned m = pm[row];
    const int g = row >> 6, l = row & 63;
    const unsigned long long bal = sbal[g];
    const unsigned long long ltm = (1ull << l) - 1ull;
    if ((m >> 16) & 1u) {
      const int p = dpre[g] + (int)__popcll(bal & ltm);
      dlist[p] = row;
      pmd[p] = m;
    } else {
      const int p = qpre[g] + (int)__popcll((~bal) & ltm);
      qlist[p] = row;
    }
  }
  if (tid < CC) {
    float tot = 0.f;
#pragma unroll
    for (int g = 0; g < 32; ++g) tot += wscol[g * CC + tid];
    colmean[tid] = tot / fmaxf((float)dpre[32], 1.f);
  }
}

// ---------------------------------------------------------------------------
// Pack donor data t-major: xd[t][dn][c] = x_all[t][dlist[dn]][c]
__global__ void transpose_kernel(const float* __restrict__ x_all,
                                 const int* __restrict__ dlist,
                                 const int* __restrict__ cnts,
                                 float* __restrict__ xd) {
  const int u = blockIdx.x * 256 + threadIdx.x;
  if (u >= T1 * NN * CC) return;
  const int t = u / (NN * CC);
  const int rem = u % (NN * CC);
  const int dn = rem >> 3;
  const int c = rem & 7;
  if (dn < cnts[0]) xd[u] = x_all[((size_t)t * NN + dlist[dn]) * DIN + c];
}

// ---------------------------------------------------------------------------
// Main: one block (256 thr = 4 waves) per QUERY. Wave w owns channels
// {2w, 2w+1}; lane = donor within group; 24 groups x 64 = 1536 slots.
// Distances held in registers (static indexing only); NO barriers in the
// main loop; selection = 5-round shuffle extraction per channel (bit-exact,
// lowest-index ties == numpy top_k). Whole grid co-resident (4 blocks/CU).
__global__ __launch_bounds__(256, 4) void knn_main(
    const float* __restrict__ x_all, const float* __restrict__ xd,
    const unsigned* __restrict__ pm, const unsigned* __restrict__ pmd,
    const int* __restrict__ qlist, const int* __restrict__ cnts,
    const float* __restrict__ colmean, float* __restrict__ out) {
  __shared__ float qlds[T1][CC];
  __shared__ float rcp17[32];
  const int nq = cnts[1];
  const int bid = blockIdx.x;
  if (bid >= nq) return;
  const int i = qlist[bid];
  const int ndon = cnts[0];
  const unsigned mi = (unsigned)__builtin_amdgcn_readfirstlane((int)pm[i]);
  const int tid = threadIdx.x;
  const int lane = tid & 63;
  const int w = tid >> 6;        // wave id
  const int c0 = w * 2;          // channels c0, c0+1

  if (tid < 32) rcp17[tid] = 17.f / (float)tid;  // [0] = inf, guarded
  if (tid < T1 * CC)
    qlds[tid >> 3][tid & 7] = x_all[((size_t)(tid >> 3) * NN + i) * DIN + (tid & 7)];
  __syncthreads();

  float dr[NG], ds2[NG];  // per-lane distances, ch c0 / c0+1 (static idx only)

#pragma unroll
  for (int b = 0; b < NB; ++b) {
    unsigned mk[8];
    float a0[8], a1[8];
#pragma unroll
    for (int j = 0; j < 8; ++j) {
      const int dn = (b * 8 + j) * 64 + lane;
      mk[j] = (dn < ndon) ? (mi & pmd[dn]) : 0u;
      a0[j] = 0.f;
      a1[j] = 0.f;
    }
    const unsigned any =
        mk[0] | mk[1] | mk[2] | mk[3] | mk[4] | mk[5] | mk[6] | mk[7];
    if (any) {  // exec-guard: fully-dead batches (and lanes) skip everything
      unsigned tm = mi & 0xFFFFu;  // scalar walk, ~8.5 iterations
      while (tm) {
        const int t = __ffs(tm) - 1;
        tm &= tm - 1u;
        const int sh = 31 - t;
        const float* __restrict__ pt = xd + (size_t)t * PLANE + c0;  // SGPR base
        const float2 qv = *(const float2*)&qlds[t][c0];
#pragma unroll
        for (int j = 0; j < 8; ++j) {
          const float2 dv = *(const float2*)(pt + ((b * 8 + j) * 64 + lane) * CC);
          const int em = ((int)(mk[j] << sh)) >> 31;  // all-ones iff bit t set
          float e;
          e = qv.x - dv.x; e = __int_as_float(__float_as_int(e) & em); a0[j] = fmaf(e, e, a0[j]);
          e = qv.y - dv.y; e = __int_as_float(__float_as_int(e) & em); a1[j] = fmaf(e, e, a1[j]);
        }
      }
    }
#pragma unroll
    for (int j = 0; j < 8; ++j) {
      const int cnt = __popc(mk[j]);
      const float sc = rcp17[cnt & 31];
      const bool ok = cnt > 0;
      dr[b * 8 + j] = ok ? sqrtf(a0[j] * sc) : INFINITY;
      ds2[b * 8 + j] = ok ? sqrtf(a1[j] * sc) : INFINITY;
    }
  }

  // ---- selection per channel: 5 extraction rounds over register values ----
  const float* __restrict__ xd16 = xd + (size_t)16 * PLANE;

  float sumA = 0.f;
  int cnA = 0;
  for (int k = 0; k < KK; ++k) {
    float g = dr[0];
#pragma unroll
    for (int u = 1; u < NG; ++u) g = fminf(g, dr[u]);
#pragma unroll
    for (int off = 32; off > 0; off >>= 1) g = fminf(g, __shfl_xor(g, off));
    if (!(g < INFINITY)) break;  // wave-uniform
    int jloc = 0x7FFFFFFF;
#pragma unroll
    for (int u = NG - 1; u >= 0; --u)
      if (dr[u] == g) jloc = u * 64 + lane;  // lowest u => lowest index
#pragma unroll
    for (int off = 32; off > 0; off >>= 1) jloc = min(jloc, __shfl_xor(jloc, off));
    const int jgs = __builtin_amdgcn_readfirstlane(jloc);
    const int tu = jgs >> 6, tl = jgs & 63;
#pragma unroll
    for (int u = 0; u < NG; ++u)
      if (u == tu) dr[u] = (lane == tl) ? INFINITY : dr[u];
    sumA += xd16[jgs * CC + c0];  // ascending (d, j) order
    ++cnA;
  }

  float sumB = 0.f;
  int cnB = 0;
  for (int k = 0; k < KK; ++k) {
    float g = ds2[0];
#pragma unroll
    for (int u = 1; u < NG; ++u) g = fminf(g, ds2[u]);
#pragma unroll
    for (int off = 32; off > 0; off >>= 1) g = fminf(g, __shfl_xor(g, off));
    if (!(g < INFINITY)) break;  // wave-uniform
    int jloc = 0x7FFFFFFF;
#pragma unroll
    for (int u = NG - 1; u >= 0; --u)
      if (ds2[u] == g) jloc = u * 64 + lane;
#pragma unroll
    for (int off = 32; off > 0; off >>= 1) jloc = min(jloc, __shfl_xor(jloc, off));
    const int jgs = __builtin_amdgcn_readfirstlane(jloc);
    const int tu = jgs >> 6, tl = jgs & 63;
#pragma unroll
    for (int u = 0; u < NG; ++u)
      if (u == tu) ds2[u] = (lane == tl) ? INFINITY : ds2[u];
    sumB += xd16[jgs * CC + c0 + 1];
    ++cnB;
  }

  if (lane == 0) {
    out[i * CC + c0] = (cnA > 0) ? sumA / (float)cnA : colmean[c0];
    out[i * CC + c0 + 1] = (cnB > 0) ? sumB / (float)cnB : colmean[c0 + 1];
  }
}

// ---------------------------------------------------------------------------
extern "C" void kernel_launch(void* const* d_in, const int* in_sizes, int n_in,
                              void* d_out, int out_size, void* d_ws, size_t ws_size,
                              hipStream_t stream) {
  const float* x_all = (const float*)d_in[0];  // [17, 2048, 9] f32
  const int* mask = (const int*)d_in[1];       // [17, 2048] i32
  float* out = (float*)d_out;                  // [2048, 8] f32

  char* ws = (char*)d_ws;
  float* xd = (float*)ws;
  unsigned* pm = (unsigned*)(ws + XD_BYTES);
  int* dlist = (int*)(ws + XD_BYTES + NN * 4);
  unsigned* pmd = (unsigned*)(ws + XD_BYTES + NN * 8);
  int* qlist = (int*)(ws + XD_BYTES + NN * 12);
  float* colmean = (float*)(ws + XD_BYTES + NN * 16);
  int* cnts = (int*)(ws + XD_BYTES + NN * 16 + CC * 4);
  unsigned long long* wsbal = (unsigned long long*)(ws + XD_BYTES + NN * 16 + CC * 4 + 64);
  float* wscol = (float*)(ws + XD_BYTES + NN * 16 + CC * 4 + 64 + 32 * 8);

  prep_a<<<16, 128, 0, stream>>>(x_all, mask, pm, wsbal, wscol, out);
  prep_b<<<1, 1024, 0, stream>>>(pm, wsbal, wscol, dlist, pmd, qlist, colmean, cnts);
  transpose_kernel<<<(T1 * NN * CC + 255) / 256, 256, 0, stream>>>(x_all, dlist, cnts, xd);
  knn_main<<<NQCAP, 256, 0, stream>>>(x_all, xd, pm, pmd, qlist, cnts, colmean, out);
}

// Round 12
// 55.772 us; speedup vs baseline: 1.1206x; 1.1206x over previous
//
#include <hip/hip_runtime.h>
#include <math.h>

#define T1 17
#define NN 2048
#define DIN 9
#define CC 8
#define KK 5
#define HDON 768               // donors per half
#define NDCAP (HDON * 2)       // 1536 slots (E[ndon]=1024, +22 sigma)
#define NQCAP 1280
#define HPAD (HDON + 8)        // 776
#define NUP (HDON / 64)        // 12 cached distances per lane
#define PLANE (NN * CC)
#define XD_BYTES (T1 * NN * CC * 4)

__device__ __forceinline__ bool lexlt(float d1, int j1, float d2, int j2) {
  return d1 < d2 || (d1 == d2 && j1 < j2);
}

// ---------------------------------------------------------------------------
__global__ __launch_bounds__(128) void prep_a(
    const float* __restrict__ x_all, const int* __restrict__ mask,
    unsigned* __restrict__ pm, unsigned long long* __restrict__ wsbal,
    float* __restrict__ wscol, float* __restrict__ out) {
  const int row = blockIdx.x * 128 + threadIdx.x;
  const int lane = threadIdx.x & 63;
  const int g = row >> 6;
  unsigned m = 0;
#pragma unroll
  for (int t = 0; t < T1; ++t)
    m |= (mask[t * NN + row] == 0 ? 1u : 0u) << t;
  pm[row] = m;
  const bool v = (m >> 16) & 1u;
  const unsigned long long bal = __ballot(v);

  float s[CC];
#pragma unroll
  for (int c = 0; c < CC; ++c) s[c] = 0.f;
  if (v) {
    const float* r = x_all + ((size_t)16 * NN + row) * DIN;
#pragma unroll
    for (int c = 0; c < CC; ++c) {
      const float vv = r[c];
      s[c] = vv;
      out[row * CC + c] = vv;
    }
  }
#pragma unroll
  for (int off = 32; off > 0; off >>= 1) {
#pragma unroll
    for (int c = 0; c < CC; ++c) s[c] += __shfl_down(s[c], off);
  }
  if (lane == 0) {
    wsbal[g] = bal;
#pragma unroll
    for (int c = 0; c < CC; ++c) wscol[g * CC + c] = s[c];
  }
}

// ---------------------------------------------------------------------------
__global__ __launch_bounds__(1024) void prep_b(
    const unsigned* __restrict__ pm, const unsigned long long* __restrict__ wsbal,
    const float* __restrict__ wscol, int* __restrict__ dlist,
    unsigned* __restrict__ pmd, int* __restrict__ qlist,
    float* __restrict__ colmean, int* __restrict__ cnts) {
  __shared__ int dpre[33], qpre[33];
  __shared__ unsigned long long sbal[32];
  const int tid = threadIdx.x;
  if (tid < 32) sbal[tid] = wsbal[tid];
  __syncthreads();
  if (tid == 0) {
    int a = 0, b = 0;
    for (int g = 0; g < 32; ++g) {
      dpre[g] = a;
      qpre[g] = b;
      const int p = (int)__popcll(sbal[g]);
      a += p;
      b += 64 - p;
    }
    dpre[32] = a;
    qpre[32] = b;
    cnts[0] = a;  // ndon
    cnts[1] = b;  // nq
  }
  __syncthreads();
#pragma unroll
  for (int h = 0; h < 2; ++h) {
    const int row = tid + h * 1024;
    const unsigned m = pm[row];
    const int g = row >> 6, l = row & 63;
    const unsigned long long bal = sbal[g];
    const unsigned long long ltm = (1ull << l) - 1ull;
    if ((m >> 16) & 1u) {
      const int p = dpre[g] + (int)__popcll(bal & ltm);
      dlist[p] = row;
      pmd[p] = m;
    } else {
      const int p = qpre[g] + (int)__popcll((~bal) & ltm);
      qlist[p] = row;
    }
  }
  if (tid < CC) {
    float tot = 0.f;
#pragma unroll
    for (int g = 0; g < 32; ++g) tot += wscol[g * CC + tid];
    colmean[tid] = tot / fmaxf((float)dpre[32], 1.f);
  }
}

// ---------------------------------------------------------------------------
// Pack donor data t-major: xd[t][dn][c] = x_all[t][dlist[dn]][c]
__global__ void transpose_kernel(const float* __restrict__ x_all,
                                 const int* __restrict__ dlist,
                                 const int* __restrict__ cnts,
                                 float* __restrict__ xd) {
  const int u = blockIdx.x * 256 + threadIdx.x;
  if (u >= T1 * NN * CC) return;
  const int t = u / (NN * CC);
  const int rem = u % (NN * CC);
  const int dn = rem >> 3;
  const int c = rem & 7;
  if (dn < cnts[0]) xd[u] = x_all[((size_t)t * NN + dlist[dn]) * DIN + c];
}

// ---------------------------------------------------------------------------
// Per-half extraction (channel CH) merging into NAMED running top-5.
// Bit-exact lowest-index ties == numpy top_k (R7-proven logic).
#define EXTRACT5(CH, RD0, RD1, RD2, RD3, RD4, RJ0, RJ1, RJ2, RJ3, RJ4)      \
  do {                                                                      \
    float dvr[NUP];                                                         \
    _Pragma("unroll")                                                       \
    for (int u = 0; u < NUP; ++u) dvr[u] = sdist[CH][u * 64 + lane];        \
    for (int k = 0; k < KK; ++k) {                                          \
      float g = dvr[0];                                                     \
      _Pragma("unroll")                                                     \
      for (int u = 1; u < NUP; ++u) g = fminf(g, dvr[u]);                   \
      _Pragma("unroll")                                                     \
      for (int off = 32; off > 0; off >>= 1) g = fminf(g, __shfl_xor(g, off)); \
      if (!(g < INFINITY)) break;                                           \
      int jloc = 0x7FFFFFFF;                                                \
      _Pragma("unroll")                                                     \
      for (int u = NUP - 1; u >= 0; --u)                                    \
        if (dvr[u] == g) jloc = u * 64 + lane;                              \
      _Pragma("unroll")                                                     \
      for (int off = 32; off > 0; off >>= 1) jloc = min(jloc, __shfl_xor(jloc, off)); \
      const int jgs = __builtin_amdgcn_readfirstlane(jloc);                 \
      const float gf = __int_as_float(__builtin_amdgcn_readfirstlane(__float_as_int(g))); \
      const int ja = pbase + jgs;                                           \
      if (!lexlt(gf, ja, RD4, RJ4)) break;                                  \
      RD4 = gf; RJ4 = ja;                                                   \
      if (lexlt(RD4, RJ4, RD3, RJ3)) { float td = RD3; RD3 = RD4; RD4 = td; int tj = RJ3; RJ3 = RJ4; RJ4 = tj; } \
      if (lexlt(RD3, RJ3, RD2, RJ2)) { float td = RD2; RD2 = RD3; RD3 = td; int tj = RJ2; RJ2 = RJ3; RJ3 = tj; } \
      if (lexlt(RD2, RJ2, RD1, RJ1)) { float td = RD1; RD1 = RD2; RD2 = td; int tj = RJ1; RJ1 = RJ2; RJ2 = tj; } \
      if (lexlt(RD1, RJ1, RD0, RJ0)) { float td = RD0; RD0 = RD1; RD1 = td; int tj = RJ0; RJ0 = RJ1; RJ1 = tj; } \
      const int tu = jgs >> 6, tl = jgs & 63;                               \
      _Pragma("unroll")                                                     \
      for (int u = 0; u < NUP; ++u)                                         \
        if (u == tu) dvr[u] = (lane == tl) ? INFINITY : dvr[u];             \
    }                                                                       \
  } while (0)

// Main: one block (256 thr) per QUERY. Lane owns a donor and computes ALL 8
// channels from the donor's contiguous 32B row (2x dwordx4, 100% cache-line
// use, wave reads contiguous 2KB). Two halves of 768 donors; distances to
// 25KB LDS; wave w extracts channels {w, w+4} (running top-5, tie-exact).
__global__ __launch_bounds__(256, 5) void knn_main(
    const float* __restrict__ x_all, const float* __restrict__ xd,
    const unsigned* __restrict__ pm, const unsigned* __restrict__ pmd,
    const int* __restrict__ qlist, const int* __restrict__ cnts,
    const float* __restrict__ colmean, float* __restrict__ out) {
  __shared__ float sdist[CC][HPAD];  // 24,832 B
  __shared__ float qlds[T1][CC];
  __shared__ float rcp17[32];
  const int nq = cnts[1];
  const int bid = blockIdx.x;
  if (bid >= nq) return;
  const int i = qlist[bid];
  const int ndon = cnts[0];
  const unsigned mi = (unsigned)__builtin_amdgcn_readfirstlane((int)pm[i]);
  const int tid = threadIdx.x;
  const int lane = tid & 63;
  const int w = tid >> 6;  // wave id: channels w, w+4

  if (tid < 32) rcp17[tid] = 17.f / (float)tid;  // [0] = inf, guarded
  if (tid < T1 * CC)
    qlds[tid >> 3][tid & 7] = x_all[((size_t)(tid >> 3) * NN + i) * DIN + (tid & 7)];
  __syncthreads();

  // running top-5 for channels A=w, B=w+4 (lex ascending (d,j)), uniform
  float rA0 = INFINITY, rA1 = INFINITY, rA2 = INFINITY, rA3 = INFINITY, rA4 = INFINITY;
  int jA0 = 0x7FFFFFFF, jA1 = 0x7FFFFFFF, jA2 = 0x7FFFFFFF, jA3 = 0x7FFFFFFF, jA4 = 0x7FFFFFFF;
  float rB0 = INFINITY, rB1 = INFINITY, rB2 = INFINITY, rB3 = INFINITY, rB4 = INFINITY;
  int jB0 = 0x7FFFFFFF, jB1 = 0x7FFFFFFF, jB2 = 0x7FFFFFFF, jB3 = 0x7FFFFFFF, jB4 = 0x7FFFFFFF;

#pragma unroll
  for (int half = 0; half < 2; ++half) {
    const int pbase = half * HDON;
    if (pbase < ndon) {  // block-uniform
      // ---- distance phase: thread covers donors pbase + j*256 + tid ----
      unsigned mk[3];
      float ac[3][CC];
#pragma unroll
      for (int j = 0; j < 3; ++j) {
        const int dn = pbase + j * 256 + tid;
        mk[j] = (dn < ndon) ? (mi & pmd[dn]) : 0u;
#pragma unroll
        for (int c = 0; c < CC; ++c) ac[j][c] = 0.f;
      }

      unsigned tm = mi & 0xFFFFu;  // SGPR sparse walk (~8.5 iters)
      while (tm) {
        const int t = __ffs(tm) - 1;
        tm &= tm - 1u;
        const int sh = 31 - t;
        const float* __restrict__ pt = xd + (size_t)t * PLANE;
        const float4 qv0 = *(const float4*)&qlds[t][0];
        const float4 qv1 = *(const float4*)&qlds[t][4];
#pragma unroll
        for (int j = 0; j < 3; ++j) {
          if (mk[j]) {  // exec-guard: dead donors issue no loads
            const float* dp = pt + (size_t)(pbase + j * 256 + tid) * CC;
            const float4 dv0 = *(const float4*)dp;
            const float4 dv1 = *(const float4*)(dp + 4);
            const int em = ((int)(mk[j] << sh)) >> 31;
            float e;
            e = qv0.x - dv0.x; e = __int_as_float(__float_as_int(e) & em); ac[j][0] = fmaf(e, e, ac[j][0]);
            e = qv0.y - dv0.y; e = __int_as_float(__float_as_int(e) & em); ac[j][1] = fmaf(e, e, ac[j][1]);
            e = qv0.z - dv0.z; e = __int_as_float(__float_as_int(e) & em); ac[j][2] = fmaf(e, e, ac[j][2]);
            e = qv0.w - dv0.w; e = __int_as_float(__float_as_int(e) & em); ac[j][3] = fmaf(e, e, ac[j][3]);
            e = qv1.x - dv1.x; e = __int_as_float(__float_as_int(e) & em); ac[j][4] = fmaf(e, e, ac[j][4]);
            e = qv1.y - dv1.y; e = __int_as_float(__float_as_int(e) & em); ac[j][5] = fmaf(e, e, ac[j][5]);
            e = qv1.z - dv1.z; e = __int_as_float(__float_as_int(e) & em); ac[j][6] = fmaf(e, e, ac[j][6]);
            e = qv1.w - dv1.w; e = __int_as_float(__float_as_int(e) & em); ac[j][7] = fmaf(e, e, ac[j][7]);
          }
        }
      }

#pragma unroll
      for (int j = 0; j < 3; ++j) {
        const int dnl = j * 256 + tid;
        const int cnt = __popc(mk[j]);
        const float sc = rcp17[cnt & 31];
        const bool ok = cnt > 0;
#pragma unroll
        for (int c = 0; c < CC; ++c)
          sdist[c][dnl] = ok ? sqrtf(ac[j][c] * sc) : INFINITY;
      }
      __syncthreads();

      // ---- extraction: wave w -> channels w and w+4 ----
      EXTRACT5(w, rA0, rA1, rA2, rA3, rA4, jA0, jA1, jA2, jA3, jA4);
      EXTRACT5(w + 4, rB0, rB1, rB2, rB3, rB4, jB0, jB1, jB2, jB3, jB4);
      __syncthreads();  // protect sdist before next half overwrites
    }
  }

  // ---- output: sum donor values in ascending (d, j) order ----
  const float* __restrict__ xd16 = xd + (size_t)16 * PLANE;
  {
    float sum = 0.f;
    int cn = 0;
    if (rA0 < INFINITY) { sum += xd16[jA0 * CC + w]; ++cn; }
    if (rA1 < INFINITY) { sum += xd16[jA1 * CC + w]; ++cn; }
    if (rA2 < INFINITY) { sum += xd16[jA2 * CC + w]; ++cn; }
    if (rA3 < INFINITY) { sum += xd16[jA3 * CC + w]; ++cn; }
    if (rA4 < INFINITY) { sum += xd16[jA4 * CC + w]; ++cn; }
    if (lane == 0) out[i * CC + w] = (cn > 0) ? sum / (float)cn : colmean[w];
  }
  {
    float sum = 0.f;
    int cn = 0;
    if (rB0 < INFINITY) { sum += xd16[jB0 * CC + w + 4]; ++cn; }
    if (rB1 < INFINITY) { sum += xd16[jB1 * CC + w + 4]; ++cn; }
    if (rB2 < INFINITY) { sum += xd16[jB2 * CC + w + 4]; ++cn; }
    if (rB3 < INFINITY) { sum += xd16[jB3 * CC + w + 4]; ++cn; }
    if (rB4 < INFINITY) { sum += xd16[jB4 * CC + w + 4]; ++cn; }
    if (lane == 0) out[i * CC + w + 4] = (cn > 0) ? sum / (float)cn : colmean[w + 4];
  }
}

// ---------------------------------------------------------------------------
extern "C" void kernel_launch(void* const* d_in, const int* in_sizes, int n_in,
                              void* d_out, int out_size, void* d_ws, size_t ws_size,
                              hipStream_t stream) {
  const float* x_all = (const float*)d_in[0];  // [17, 2048, 9] f32
  const int* mask = (const int*)d_in[1];       // [17, 2048] i32
  float* out = (float*)d_out;                  // [2048, 8] f32

  char* ws = (char*)d_ws;
  float* xd = (float*)ws;
  unsigned* pm = (unsigned*)(ws + XD_BYTES);
  int* dlist = (int*)(ws + XD_BYTES + NN * 4);
  unsigned* pmd = (unsigned*)(ws + XD_BYTES + NN * 8);
  int* qlist = (int*)(ws + XD_BYTES + NN * 12);
  float* colmean = (float*)(ws + XD_BYTES + NN * 16);
  int* cnts = (int*)(ws + XD_BYTES + NN * 16 + CC * 4);
  unsigned long long* wsbal = (unsigned long long*)(ws + XD_BYTES + NN * 16 + CC * 4 + 64);
  float* wscol = (float*)(ws + XD_BYTES + NN * 16 + CC * 4 + 64 + 32 * 8);

  prep_a<<<16, 128, 0, stream>>>(x_all, mask, pm, wsbal, wscol, out);
  prep_b<<<1, 1024, 0, stream>>>(pm, wsbal, wscol, dlist, pmd, qlist, colmean, cnts);
  transpose_kernel<<<(T1 * NN * CC + 255) / 256, 256, 0, stream>>>(x_all, dlist, cnts, xd);
  knn_main<<<NQCAP, 256, 0, stream>>>(x_all, xd, pm, pmd, qlist, cnts, colmean, out);
}